// Round 1
// baseline (278.191 us; speedup 1.0000x reference)
//
#include <hip/hip_runtime.h>
#include <math.h>

// Problem constants (from setup_inputs): N=16, T=2048, C=512, V=1024.
#define TT 2048
#define CC 512
#define VV 1024

// ---------------------------------------------------------------------------
// Kernel A: per-frame keep flags.
// keep[t] = (blank_lp[t] < log(0.95) && t < x_len)            (non-blank, unpadded)
//         || (desc_rank(t) >= T - y_len)                       (forced-keep: y_len smallest blank_lp)
// desc_rank(t) = #{s: v_s > v_t} + #{s: v_s == v_t && s < t}   (matches stable argsort-argsort)
// Grid: (T/256, N). Each block stages the full blank column (2048 f32 = 8 KB)
// in LDS; lockstep s-loop -> LDS broadcast reads (conflict-free).
// ---------------------------------------------------------------------------
__global__ __launch_bounds__(256) void flags_kernel(
    const float* __restrict__ ctc, const int* __restrict__ x_lens,
    const int* __restrict__ y_lens, const int* __restrict__ blank_id,
    int* __restrict__ flags) {
  const int n = blockIdx.y;
  const int chunk = blockIdx.x;
  __shared__ float sv[TT];
  const int bid = blank_id[0];
  const float* row = ctc + (size_t)n * TT * VV + bid;
  for (int i = threadIdx.x; i < TT; i += 256) sv[i] = row[(size_t)i * VV];
  __syncthreads();

  const int t = chunk * 256 + threadIdx.x;
  const float vt = sv[t];
  int cnt = 0;
#pragma unroll 8
  for (int s = 0; s < TT; ++s) {
    float w = sv[s];
    cnt += (w > vt || (w == vt && s < t)) ? 1 : 0;
  }
  const int limit = TT - y_lens[n];
  const float LOG_T = (float)-0.05129329438755058;  // float32(log(0.95))
  const int keep = ((vt < LOG_T) && (t < x_lens[n])) || (cnt >= limit);
  flags[n * TT + t] = keep;
}

// ---------------------------------------------------------------------------
// Kernel B: per-row exclusive scan of flags -> gather map (src frame index per
// output slot) + out_lens (int for kernel C, float into d_out tail).
// Grid: N blocks x 256 threads, 8 flags/thread.
// ---------------------------------------------------------------------------
__global__ __launch_bounds__(256) void scan_kernel(
    const int* __restrict__ flags, int* __restrict__ src_map,
    int* __restrict__ out_lens_i, float* __restrict__ out_lens_f) {
  const int n = blockIdx.x;
  const int tid = threadIdx.x;
  int f[8];
  const int base = n * TT + tid * 8;
  int local = 0;
#pragma unroll
  for (int k = 0; k < 8; ++k) {
    f[k] = flags[base + k];
    local += f[k];
  }
  __shared__ int ssum[256];
  ssum[tid] = local;
  __syncthreads();
  // Hillis-Steele inclusive scan over 256 thread sums.
  for (int off = 1; off < 256; off <<= 1) {
    int v = (tid >= off) ? ssum[tid - off] : 0;
    __syncthreads();
    ssum[tid] += v;
    __syncthreads();
  }
  int pos = ssum[tid] - local;  // exclusive prefix for this thread's chunk
  const int total = ssum[255];
#pragma unroll
  for (int k = 0; k < 8; ++k) {
    if (f[k]) {
      src_map[n * TT + pos] = tid * 8 + k;
      ++pos;
    }
  }
  if (tid == 0) {
    out_lens_i[n] = total;
    out_lens_f[n] = (float)total;
  }
}

// ---------------------------------------------------------------------------
// Kernel C: gather kept frames to the front, zero the tail.
// One float4 per thread; writes fully coalesced; reads coalesced within a
// 2 KB source row. Grid: N*T*C/4/256 = 16384 blocks.
// ---------------------------------------------------------------------------
__global__ __launch_bounds__(256) void gather_kernel(
    const float4* __restrict__ x, const int* __restrict__ src_map,
    const int* __restrict__ out_lens_i, float4* __restrict__ out) {
  const size_t idx = (size_t)blockIdx.x * 256 + threadIdx.x;
  const int c4 = (int)(idx & 127);          // C/4 = 128
  const size_t row = idx >> 7;
  const int j = (int)(row & (TT - 1));
  const int n = (int)(row >> 11);           // /T
  float4 val;
  if (j < out_lens_i[n]) {
    const int src = src_map[n * TT + j];
    val = x[(((size_t)n * TT + src) << 7) + c4];
  } else {
    val = make_float4(0.f, 0.f, 0.f, 0.f);
  }
  out[idx] = val;
}

extern "C" void kernel_launch(void* const* d_in, const int* in_sizes, int n_in,
                              void* d_out, int out_size, void* d_ws, size_t ws_size,
                              hipStream_t stream) {
  const float* x = (const float*)d_in[0];
  const int* x_lens = (const int*)d_in[1];
  const float* ctc = (const float*)d_in[2];
  const int* y_lens = (const int*)d_in[3];
  const int* blank_id = (const int*)d_in[4];
  float* out = (float*)d_out;
  const int N = in_sizes[1];  // 16

  int* flags = (int*)d_ws;                 // N*T ints
  int* src_map = flags + N * TT;           // N*T ints
  int* out_lens_i = src_map + N * TT;      // N ints
  float* out_lens_f = out + (size_t)N * TT * CC;  // tail of d_out, as f32

  flags_kernel<<<dim3(TT / 256, N), 256, 0, stream>>>(ctc, x_lens, y_lens,
                                                      blank_id, flags);
  scan_kernel<<<N, 256, 0, stream>>>(flags, src_map, out_lens_i, out_lens_f);

  const int total4 = N * TT * (CC / 4);
  gather_kernel<<<total4 / 256, 256, 0, stream>>>((const float4*)x, src_map,
                                                  out_lens_i, (float4*)out);
}

// Round 2
// 228.749 us; speedup vs baseline: 1.2161x; 1.2161x over previous
//
#include <hip/hip_runtime.h>

// Problem constants (from setup_inputs): N=16, T=2048, C=512, V=1024.
#define TT 2048
#define CC 512
#define VV 1024
#define NTHR 256
#define EPT 8  // elements per thread = TT / NTHR

// Monotone total-order key: ascending float  <=>  ascending uint key.
__device__ __forceinline__ unsigned int fkey(float f) {
  unsigned int b = __float_as_uint(f);
  return b ^ ((b & 0x80000000u) ? 0xFFFFFFFFu : 0x80000000u);
}

// Inclusive scan of one int per thread across a 256-thread block.
// Wave(64)-level shfl scan + 4-entry LDS combine; 2 barriers.
__device__ __forceinline__ int block_scan_incl(int v, int* wsum, int tid) {
#pragma unroll
  for (int off = 1; off < 64; off <<= 1) {
    int u = __shfl_up(v, off, 64);
    if ((tid & 63) >= off) v += u;
  }
  const int wave = tid >> 6;
  if ((tid & 63) == 63) wsum[wave] = v;
  __syncthreads();
  int add = 0;
#pragma unroll
  for (int w = 0; w < 3; ++w) add += (w < wave) ? wsum[w] : 0;
  v += add;
  __syncthreads();  // protect wsum reuse by the next scan
  return v;
}

// ---------------------------------------------------------------------------
// Fused kernel: per row (one block of 256 threads):
//   1) load blank column, build monotone keys (8/thread, registers only)
//   2) radix-select (4 x 8-bit rounds) the y_len-th smallest key  (theta)
//   3) exact stable tie-break: forced(t) <=> key<theta
//          || (key==theta && eq_prefix(t) >= M - Kp)   [last Kp tied indices]
//   4) keep(t) = (key < key(log 0.95) && t < x_len) || forced(t)
//   5) block scan of keep flags -> compacted src_map + out_lens
// ---------------------------------------------------------------------------
__global__ __launch_bounds__(256) void select_scan_kernel(
    const float* __restrict__ ctc, const int* __restrict__ x_lens,
    const int* __restrict__ y_lens, const int* __restrict__ blank_id,
    int* __restrict__ src_map, int* __restrict__ out_lens_i,
    float* __restrict__ out_lens_f) {
  const int n = blockIdx.x;
  const int tid = threadIdx.x;
  __shared__ int hist[256];
  __shared__ int wsum[4];
  __shared__ int bsel[3];  // [0]=bin, [1]=new Kp, [2]=bin count (M at r==0)
  __shared__ int stotal;

  const int bid = blank_id[0];
  const float* row = ctc + (size_t)n * TT * VV + bid;
  unsigned int myk[EPT];
#pragma unroll
  for (int k = 0; k < EPT; ++k) {
    const int t = tid * EPT + k;
    myk[k] = fkey(row[(size_t)t * VV]);
  }

  // ---- radix select: find theta = key of the Kp-th smallest (1-based) ----
  int Kp = y_lens[n];  // in [64, 511], <= TT
  unsigned int prefix = 0;
  int M = 0;
#pragma unroll
  for (int r = 3; r >= 0; --r) {
    hist[tid] = 0;
    __syncthreads();
    const int sh = r * 8;
#pragma unroll
    for (int k = 0; k < EPT; ++k) {
      const unsigned int u = myk[k];
      // active iff high bytes (above byte r) match the fixed prefix
      const bool act =
          (r == 3) || (((unsigned long long)u >> (sh + 8)) ==
                       ((unsigned long long)prefix >> (sh + 8)));
      if (act) atomicAdd(&hist[(u >> sh) & 0xFF], 1);
    }
    __syncthreads();
    const int own = hist[tid];
    const int cum = block_scan_incl(own, wsum, tid);
    const int excl = cum - own;
    if (own > 0 && excl < Kp && cum >= Kp) {  // exactly one thread
      bsel[0] = tid;
      bsel[1] = Kp - excl;
      bsel[2] = own;
    }
    __syncthreads();
    prefix |= ((unsigned int)bsel[0]) << sh;
    Kp = bsel[1];
    if (r == 0) M = bsel[2];  // #{key == theta}
  }
  const unsigned int theta = prefix;

  // ---- eq-prefix scan (for stable tie-break among key==theta) ----
  int eqc = 0;
#pragma unroll
  for (int k = 0; k < EPT; ++k) eqc += (myk[k] == theta) ? 1 : 0;
  const int eq_incl = block_scan_incl(eqc, wsum, tid);
  int e = eq_incl - eqc;  // #{s < my chunk start : key_s == theta}

  // ---- keep flags ----
  const unsigned int KEY_THR = fkey((float)-0.05129329438755058);  // log(0.95)
  const int xl = x_lens[n];
  int keepf[EPT];
  int kc = 0;
#pragma unroll
  for (int k = 0; k < EPT; ++k) {
    const int t = tid * EPT + k;
    const unsigned int u = myk[k];
    const bool eq = (u == theta);
    const bool forced = (u < theta) || (eq && (e >= M - Kp));
    const bool keep = ((u < KEY_THR) && (t < xl)) || forced;
    if (eq) ++e;
    keepf[k] = keep ? 1 : 0;
    kc += keepf[k];
  }

  // ---- compaction scan + scatter ----
  const int k_incl = block_scan_incl(kc, wsum, tid);
  int pos = k_incl - kc;
  if (tid == NTHR - 1) stotal = k_incl;
  int* smrow = src_map + n * TT;
#pragma unroll
  for (int k = 0; k < EPT; ++k) {
    if (keepf[k]) smrow[pos++] = tid * EPT + k;
  }
  __syncthreads();
  if (tid == 0) {
    out_lens_i[n] = stotal;
    out_lens_f[n] = (float)stotal;
  }
}

// ---------------------------------------------------------------------------
// Gather kept frames to the front, zero the tail. One float4 per thread,
// fully coalesced writes. Grid: N*T*C/4/256 = 16384 blocks.
// ---------------------------------------------------------------------------
__global__ __launch_bounds__(256) void gather_kernel(
    const float4* __restrict__ x, const int* __restrict__ src_map,
    const int* __restrict__ out_lens_i, float4* __restrict__ out) {
  const size_t idx = (size_t)blockIdx.x * 256 + threadIdx.x;
  const int c4 = (int)(idx & 127);  // C/4 = 128
  const size_t row = idx >> 7;
  const int j = (int)(row & (TT - 1));
  const int n = (int)(row >> 11);  // / T
  float4 val;
  if (j < out_lens_i[n]) {
    const int src = src_map[n * TT + j];
    val = x[(((size_t)n * TT + src) << 7) + c4];
  } else {
    val = make_float4(0.f, 0.f, 0.f, 0.f);
  }
  out[idx] = val;
}

extern "C" void kernel_launch(void* const* d_in, const int* in_sizes, int n_in,
                              void* d_out, int out_size, void* d_ws, size_t ws_size,
                              hipStream_t stream) {
  const float* x = (const float*)d_in[0];
  const int* x_lens = (const int*)d_in[1];
  const float* ctc = (const float*)d_in[2];
  const int* y_lens = (const int*)d_in[3];
  const int* blank_id = (const int*)d_in[4];
  float* out = (float*)d_out;
  const int N = in_sizes[1];  // 16

  int* src_map = (int*)d_ws;            // N*T ints
  int* out_lens_i = src_map + N * TT;   // N ints
  float* out_lens_f = out + (size_t)N * TT * CC;  // tail of d_out, as f32

  select_scan_kernel<<<N, NTHR, 0, stream>>>(ctc, x_lens, y_lens, blank_id,
                                             src_map, out_lens_i, out_lens_f);

  const int total4 = N * TT * (CC / 4);
  gather_kernel<<<total4 / 256, 256, 0, stream>>>((const float4*)x, src_map,
                                                  out_lens_i, (float4*)out);
}